// Round 7
// baseline (8459.540 us; speedup 1.0000x reference)
//
#include <hip/hip_runtime.h>

// ---------------------------------------------------------------------------
// Scaled HMM forward, B=32 rows, T=10000 serial steps, N=132 states.
// ROUND-7 = round-6 design, compile fix only (the #error guard fired on the
// HOST pass; device code was never built).
// Recurrence entirely in MFMA fragments:
//   D'[j][b] = sum_i At[j][i] * Y[i][b]   (At = A^T, resident in 162 regs)
// Layout identity for v_mfma_f32_16x16x16_f16:
//   D rows  = (lane>>4)*4 + reg
//   B k-idx = (lane>>4)*4 + elem          -> SAME lanes, SAME slots.
// So step t's f32 output fragment converts in-lane (pkrtz) to step t+1's
// f16 B-operand fragment. Zero LDS round-trip / shuffles in the matvec.
// Normalization: z_b = column sum via per-lane dot2 partials + 2 shfl_xor;
// 1-lag scale g = 128*rcp(z_prev); exact log bookkeeping:
//   sum_t ln z_t - T ln 128 = ln P   (derived: z_t = 128 s_t / s_{t-1})
// em[.][o_t]: 9 ds_read_b64 prefetched one step ahead; obs 8 steps ahead.
// 2 blocks x 64 threads; block handles 16 batch columns (b = lane&15).
// ---------------------------------------------------------------------------

typedef _Float16 half_t;
typedef half_t h2 __attribute__((ext_vector_type(2)));
typedef half_t half4 __attribute__((ext_vector_type(4)));
typedef float  f32x4 __attribute__((ext_vector_type(4)));

#define FDOT2(a, b, acc) __builtin_amdgcn_fdot2((a), (b), (acc), false)

#define NS 132
#define NSP 144        // padded states: 9 tiles of 16
#define NA 126
#define TLEN 10000
#define NBATCH 32

// workspace layout (bytes)
#define OBS_OFF 0                 // 32*10000*2       = 640000
#define AT_OFF  640000            // 81*64*8 (uint2)  = 41472
#define EM_OFF  (640000+41472)    // 126*144*2        = 36288
#define I0_OFF  (640000+41472+36288) // 144*4         = 576

static __device__ __forceinline__ h2 bch2(unsigned int u) {
    return __builtin_bit_cast(h2, u);
}
static __device__ __forceinline__ unsigned int bcu(h2 v) {
    return __builtin_bit_cast(unsigned int, v);
}
static __device__ __forceinline__ h2 pkrtz(float a, float b) {
    return __builtin_bit_cast(h2, __builtin_amdgcn_cvt_pkrtz(a, b));
}
static __device__ __forceinline__ half4 mk4(h2 a, h2 b) {
    uint2 u = make_uint2(bcu(a), bcu(b));
    return __builtin_bit_cast(half4, u);
}

// ---------------------------------------------------------------------------
// one-hot [B*T, 126] fp32 -> index [B*T] ushort. One wave per (b,t).
// ---------------------------------------------------------------------------
__global__ void onehot_to_idx_kernel(const float* __restrict__ x,
                                     unsigned short* __restrict__ obs, int total) {
    int wid  = (int)((blockIdx.x * blockDim.x + threadIdx.x) >> 6);
    int lane = threadIdx.x & 63;
    if (wid >= total) return;
    const float* row = x + (size_t)wid * NA;
    float v0 = row[lane];
    float v1 = (lane < NA - 64) ? row[64 + lane] : 0.0f;
    unsigned long long b0 = __ballot(v0 > 0.5f);
    unsigned long long b1 = __ballot(v1 > 0.5f);
    int idx = b0 ? (__ffsll(b0) - 1) : (64 + __ffsll(b1) - 1);
    if (lane == 0) obs[wid] = (unsigned short)idx;
}

// A-operand fragments: tile (jt, ic), lane l, elems e=0..3:
//   At[j][i] with j = jt*16 + (l&15), i = ic*16 + (l>>4)*4 + e
//   value = A_hmm[i][j]  (0 outside 132x132)
__global__ void pack_At_kernel(const float* __restrict__ A, uint2* __restrict__ Ah) {
    int idx = blockIdx.x * 256 + threadIdx.x;
    if (idx >= 81 * 64) return;
    int tile = idx >> 6, l = idx & 63;
    int jt = tile / 9, ic = tile % 9;
    int j  = jt * 16 + (l & 15);
    int i0 = ic * 16 + ((l >> 4) << 2);
    float v[4];
#pragma unroll
    for (int e = 0; e < 4; ++e) {
        int i = i0 + e;
        v[e] = (i < NS && j < NS) ? A[i * NS + j] : 0.0f;
    }
    h2 p01 = {(half_t)v[0], (half_t)v[1]};
    h2 p23 = {(half_t)v[2], (half_t)v[3]};
    Ah[idx] = make_uint2(bcu(p01), bcu(p23));
}

// emt[o][j] = f16(B[j][o]) for j<132, else 0.  [126][144]
__global__ void pack_em_kernel(const float* __restrict__ B, half_t* __restrict__ emt) {
    int idx = blockIdx.x * 256 + threadIdx.x;
    if (idx >= NA * NSP) return;
    int o = idx / NSP, j = idx % NSP;
    emt[idx] = (j < NS) ? (half_t)B[j * NA + o] : (half_t)0.f;
}

// I0 padded to 144 with zeros (f32)
__global__ void pack_I0_kernel(const float* __restrict__ I0, float* __restrict__ I0p) {
    int i = threadIdx.x;
    if (i < NSP) I0p[i] = (i < NS) ? I0[i] : 0.f;
}

// ---------------------------------------------------------------------------
// The serial scan. 2 blocks x 64 threads. Block handles batch cols
// [16*blk, 16*blk+15]; b = lane&15, row-groups = lane>>4.
// ---------------------------------------------------------------------------
__global__ __launch_bounds__(64)
__attribute__((amdgpu_waves_per_eu(1, 1)))
void hmm_mfma_kernel(
    const uint2* __restrict__ Ah,       // [81][64] A-frags
    const half_t* __restrict__ emt,     // [126][144]
    const float* __restrict__ I0p,      // [144]
    const unsigned short* __restrict__ obs,
    float* __restrict__ out)
{
    // 128 rows so that a masked garbage o (<=127) still reads in-bounds
    __shared__ __align__(16) half_t sEm[128 * NSP];   // 36864 B

    const int l   = threadIdx.x;
    const int blk = blockIdx.x;
    const int g4  = (l >> 4) << 2;          // row-group offset (0,4,8,12)

    // stage emission table (126 rows) into LDS
    {
        const uint4* src = (const uint4*)emt;
        uint4* dst = (uint4*)sEm;
        for (int k = l; k < (NA * NSP) / 8; k += 64) dst[k] = src[k];
    }

    // resident A-operand fragments: 81 tiles x 2 VGPRs (AGPR exile is fine --
    // MFMA reads the A operand from AGPRs natively)
    half4 at_[9][9];
#pragma unroll
    for (int jt = 0; jt < 9; ++jt)
#pragma unroll
        for (int ic = 0; ic < 9; ++ic)
            at_[jt][ic] = __builtin_bit_cast(half4, Ah[(jt * 9 + ic) * 64 + l]);

    const unsigned short* ob = obs + (size_t)(blk * 16 + (l & 15)) * TLEN;
    uint4 pk = *(const uint4*)ob;           // obs t=0..7 for this lane's column
    __syncthreads();                        // sEm staged

    const h2 ones = {(half_t)1.f, (half_t)1.f};
    half4 y_[9];
    uint2 emc[9], emn[9];
    float zp, lp, ll = 0.f;

    // ---- t = 0: Y0[i][b] = 128 * I0[i] * em[i][o0(b)] ----
    {
        int o0 = pk.x & 127;
#pragma unroll
        for (int ic = 0; ic < 9; ++ic)
            emc[ic] = *(const uint2*)&sEm[o0 * NSP + ic * 16 + g4];
        float zs = 0.f;
#pragma unroll
        for (int ic = 0; ic < 9; ++ic) {
            float4 iv = *(const float4*)&I0p[ic * 16 + g4];
            h2 e01 = bch2(emc[ic].x), e23 = bch2(emc[ic].y);
            h2 p01 = pkrtz(iv.x * (float)e01.x * 128.f, iv.y * (float)e01.y * 128.f);
            h2 p23 = pkrtz(iv.z * (float)e23.x * 128.f, iv.w * (float)e23.y * 128.f);
            y_[ic] = mk4(p01, p23);
            zs = FDOT2(p01, ones, FDOT2(p23, ones, zs));
        }
        zs += __shfl_xor(zs, 16, 64);
        zs += __shfl_xor(zs, 32, 64);
        zp = zs;
        lp = zs;                            // accumulates z_0
        // load em for step t=1
        int o1 = (pk.x >> 16) & 127;
#pragma unroll
        for (int ic = 0; ic < 9; ++ic)
            emc[ic] = *(const uint2*)&sEm[o1 * NSP + ic * 16 + g4];
    }

// obs element k (0..7) from a uint4 of packed u16
#define GETO(P, K) ((int)(((&(P).x)[(K) >> 1] >> (((K) & 1) * 16)) & 127))

// one HMM step. On entry: emc = em[., o_t], y_ = Y_{t-1} frags, zp = z_{t-1}.
#define STEP(O_NEXT, FOLD) do {                                               \
    const int _on = (O_NEXT);                                                 \
    _Pragma("unroll")                                                         \
    for (int ic = 0; ic < 9; ++ic)                                            \
        emn[ic] = *(const uint2*)&sEm[_on * NSP + ic * 16 + g4];              \
    f32x4 d[9];                                                               \
    _Pragma("unroll")                                                         \
    for (int jt = 0; jt < 9; ++jt) d[jt] = (f32x4){0.f, 0.f, 0.f, 0.f};       \
    _Pragma("unroll")                                                         \
    for (int ic = 0; ic < 9; ++ic) {                                          \
        _Pragma("unroll")                                                     \
        for (int jt = 0; jt < 9; ++jt)                                        \
            d[jt] = __builtin_amdgcn_mfma_f32_16x16x16f16(                    \
                        at_[jt][ic], y_[ic], d[jt], 0, 0, 0);                 \
    }                                                                         \
    const float gsc = 128.f * __builtin_amdgcn_rcpf(zp);                      \
    const half_t gh = (half_t)gsc;                                            \
    const h2 g2 = {gh, gh};                                                   \
    float zs = 0.f;                                                           \
    _Pragma("unroll")                                                         \
    for (int jt = 0; jt < 9; ++jt) {                                          \
        h2 p01 = pkrtz(d[jt][0], d[jt][1]) * bch2(emc[jt].x) * g2;            \
        h2 p23 = pkrtz(d[jt][2], d[jt][3]) * bch2(emc[jt].y) * g2;            \
        y_[jt] = mk4(p01, p23);                                               \
        zs = FDOT2(p01, ones, FDOT2(p23, ones, zs));                          \
    }                                                                         \
    zs += __shfl_xor(zs, 16, 64);                                             \
    zs += __shfl_xor(zs, 32, 64);                                             \
    zp = zs;                                                                  \
    lp *= zs;                                                                 \
    if (FOLD) { ll += __logf(lp); lp = 1.f; }                                 \
    _Pragma("unroll")                                                         \
    for (int ic = 0; ic < 9; ++ic) emc[ic] = emn[ic];                         \
} while (0)

    // ---- peeled chunk 0: steps t = 1..7 ----
    {
        uint4 pn = *(const uint4*)(ob + 8);
#pragma unroll
        for (int k = 1; k < 8; ++k) {
            int on = (k < 7) ? GETO(pk, k + 1) : (int)(pn.x & 127);
            STEP(on, (k & 3) == 3);
        }
        pk = pn;
    }

    // ---- main chunks: c = 1..1249, steps t = 8c..8c+7 ----
    for (int c = 1; c < 1250; ++c) {
        // prefetch next obs pack (c=1249 reads past row end into ws -- valid
        // memory; the value is masked to <=127 and never used in math)
        uint4 pn = *(const uint4*)(ob + 8 * (c + 1));
#pragma unroll
        for (int k = 0; k < 8; ++k) {
            int on = (k < 7) ? GETO(pk, k + 1) : (int)(pn.x & 127);
            STEP(on, (k & 3) == 3);
        }
        pk = pn;
    }
    // folds at t=3,7,11,...,9999 -> every z_t folded exactly once

    if (l < 16) out[blk * 16 + l] = ll - 48520.302639196f;  // 10000*ln(128)
}

// ---------------------------------------------------------------------------
extern "C" void kernel_launch(void* const* d_in, const int* in_sizes, int n_in,
                              void* d_out, int out_size, void* d_ws, size_t ws_size,
                              hipStream_t stream) {
    const float* x  = (const float*)d_in[0];  // [32,10000,126] one-hot fp32
    const float* A  = (const float*)d_in[1];  // [132,132]
    const float* Bm = (const float*)d_in[2];  // [132,126]
    const float* I0 = (const float*)d_in[3];  // [132]
    float* out = (float*)d_out;               // [32] fp32

    char* ws = (char*)d_ws;
    unsigned short* obs = (unsigned short*)(ws + OBS_OFF);
    uint2*  Ah  = (uint2*)(ws + AT_OFF);
    half_t* emt = (half_t*)(ws + EM_OFF);
    float*  I0p = (float*)(ws + I0_OFF);

    const int total = NBATCH * TLEN;
    onehot_to_idx_kernel<<<(total + 3) / 4, 256, 0, stream>>>(x, obs, total);
    pack_At_kernel<<<(81 * 64 + 255) / 256, 256, 0, stream>>>(A, Ah);
    pack_em_kernel<<<(NA * NSP + 255) / 256, 256, 0, stream>>>(Bm, emt);
    pack_I0_kernel<<<1, NSP, 0, stream>>>(I0, I0p);
    hmm_mfma_kernel<<<2, 64, 0, stream>>>(Ah, emt, I0p, obs, out);
}

// Round 8
// 7536.449 us; speedup vs baseline: 1.1225x; 1.1225x over previous
//
#include <hip/hip_runtime.h>

// ---------------------------------------------------------------------------
// Scaled HMM forward, B=32 rows, T=10000 serial steps, N=132 states.
// ROUND-8: round-7 MFMA-resident recurrence (verified absmax 0.0) + kill the
// exposed-latency tail (round 7: 2023 cy/step = 324 MFMA + ~1700 stall):
//  * permlane16/32_swap (VALU) replace shfl_xor (DS-pipe ~120cy each)
//  * em stride 148 (74 dwords, even spread) vs 144 (72: 8-way conflicts)
//  * z-sum via 4 independent FDOT2 chains + tree (depth 18 -> 5)
//  * g = 128*rcp(zp) hoisted above MFMA block (latency hides under issue)
//  * shared zero-quad C-in for first MFMA (no 36 zero-movs/step)
// Recurrence: D'[j][b] = sum_i At[j][i] * Y[i][b]; 16x16x16f16 layout
// identity (D rows == B k-slots, per-lane) keeps it in registers.
// ---------------------------------------------------------------------------

typedef _Float16 half_t;
typedef half_t h2 __attribute__((ext_vector_type(2)));
typedef half_t half4 __attribute__((ext_vector_type(4)));
typedef float  f32x4 __attribute__((ext_vector_type(4)));
typedef unsigned int uint2v __attribute__((ext_vector_type(2)));

#define FDOT2(a, b, acc) __builtin_amdgcn_fdot2((a), (b), (acc), false)

#define NS 132
#define NSP 144        // padded states: 9 tiles of 16
#define NA 126
#define EMS 148        // em row stride in halves (296 B: 8B-aligned, bank-spread)
#define TLEN 10000
#define NBATCH 32

// workspace layout (bytes)
#define OBS_OFF 0                    // 32*10000*2      = 640000
#define AT_OFF  640000               // 81*64*8 (uint2) = 41472
#define EM_OFF  (640000+41472)       // 126*148*2       = 37296
#define I0_OFF  (EM_OFF+NA*EMS*2)    // 144*4           = 576

static __device__ __forceinline__ h2 bch2(unsigned int u) {
    return __builtin_bit_cast(h2, u);
}
static __device__ __forceinline__ unsigned int bcu(h2 v) {
    return __builtin_bit_cast(unsigned int, v);
}
static __device__ __forceinline__ h2 pkrtz(float a, float b) {
    return __builtin_bit_cast(h2, __builtin_amdgcn_cvt_pkrtz(a, b));
}
static __device__ __forceinline__ half4 mk4(h2 a, h2 b) {
    uint2 u = make_uint2(bcu(a), bcu(b));
    return __builtin_bit_cast(half4, u);
}

// lane-crossing adds on the VALU (gfx950 permlane*_swap), DS-pipe fallback
static __device__ __forceinline__ float xadd16(float v) {
#if __has_builtin(__builtin_amdgcn_permlane16_swap)
    uint2v r = __builtin_amdgcn_permlane16_swap(
        __builtin_bit_cast(unsigned int, v), __builtin_bit_cast(unsigned int, v),
        false, false);
    return __builtin_bit_cast(float, r[0]) + __builtin_bit_cast(float, r[1]);
#else
    return v + __shfl_xor(v, 16, 64);
#endif
}
static __device__ __forceinline__ float xadd32(float v) {
#if __has_builtin(__builtin_amdgcn_permlane32_swap)
    uint2v r = __builtin_amdgcn_permlane32_swap(
        __builtin_bit_cast(unsigned int, v), __builtin_bit_cast(unsigned int, v),
        false, false);
    return __builtin_bit_cast(float, r[0]) + __builtin_bit_cast(float, r[1]);
#else
    return v + __shfl_xor(v, 32, 64);
#endif
}

// ---------------------------------------------------------------------------
// one-hot [B*T, 126] fp32 -> index [B*T] ushort. One wave per (b,t).
// ---------------------------------------------------------------------------
__global__ void onehot_to_idx_kernel(const float* __restrict__ x,
                                     unsigned short* __restrict__ obs, int total) {
    int wid  = (int)((blockIdx.x * blockDim.x + threadIdx.x) >> 6);
    int lane = threadIdx.x & 63;
    if (wid >= total) return;
    const float* row = x + (size_t)wid * NA;
    float v0 = row[lane];
    float v1 = (lane < NA - 64) ? row[64 + lane] : 0.0f;
    unsigned long long b0 = __ballot(v0 > 0.5f);
    unsigned long long b1 = __ballot(v1 > 0.5f);
    int idx = b0 ? (__ffsll(b0) - 1) : (64 + __ffsll(b1) - 1);
    if (lane == 0) obs[wid] = (unsigned short)idx;
}

// A-operand fragments: tile (jt, ic), lane l, elems e=0..3:
//   At[j][i] with j = jt*16 + (l&15), i = ic*16 + (l>>4)*4 + e
__global__ void pack_At_kernel(const float* __restrict__ A, uint2* __restrict__ Ah) {
    int idx = blockIdx.x * 256 + threadIdx.x;
    if (idx >= 81 * 64) return;
    int tile = idx >> 6, l = idx & 63;
    int jt = tile / 9, ic = tile % 9;
    int j  = jt * 16 + (l & 15);
    int i0 = ic * 16 + ((l >> 4) << 2);
    float v[4];
#pragma unroll
    for (int e = 0; e < 4; ++e) {
        int i = i0 + e;
        v[e] = (i < NS && j < NS) ? A[i * NS + j] : 0.0f;
    }
    h2 p01 = {(half_t)v[0], (half_t)v[1]};
    h2 p23 = {(half_t)v[2], (half_t)v[3]};
    Ah[idx] = make_uint2(bcu(p01), bcu(p23));
}

// emt[o][j] = f16(B[j][o]) for j<132, else 0.  [126][EMS]
__global__ void pack_em_kernel(const float* __restrict__ B, half_t* __restrict__ emt) {
    int idx = blockIdx.x * 256 + threadIdx.x;
    if (idx >= NA * EMS) return;
    int o = idx / EMS, j = idx % EMS;
    emt[idx] = (j < NS) ? (half_t)B[j * NA + o] : (half_t)0.f;
}

// I0 padded to 144 with zeros (f32)
__global__ void pack_I0_kernel(const float* __restrict__ I0, float* __restrict__ I0p) {
    int i = threadIdx.x;
    if (i < NSP) I0p[i] = (i < NS) ? I0[i] : 0.f;
}

// ---------------------------------------------------------------------------
// The serial scan. 2 blocks x 64 threads. Block handles batch cols
// [16*blk, 16*blk+15]; b = lane&15, row-groups = lane>>4.
// ---------------------------------------------------------------------------
__global__ __launch_bounds__(64)
__attribute__((amdgpu_waves_per_eu(1, 1)))
void hmm_mfma_kernel(
    const uint2* __restrict__ Ah,       // [81][64] A-frags
    const half_t* __restrict__ emt,     // [126][EMS]
    const float* __restrict__ I0p,      // [144]
    const unsigned short* __restrict__ obs,
    float* __restrict__ out)
{
    // 128 rows so a masked garbage o (<=127) still reads in-bounds
    __shared__ __align__(16) half_t sEm[128 * EMS];   // 37888 B

    const int l   = threadIdx.x;
    const int blk = blockIdx.x;
    const int g4  = (l >> 4) << 2;          // row-group offset (0,4,8,12)

    // stage emission table (126 rows) into LDS
    {
        const uint2* src = (const uint2*)emt;
        uint2* dst = (uint2*)sEm;
        for (int k = l; k < (NA * EMS) / 4; k += 64) dst[k] = src[k];
    }

    // resident A-operand fragments: 81 tiles x 2 VGPRs (AGPR exile harmless --
    // MFMA reads the A operand from AGPRs natively)
    half4 at_[9][9];
#pragma unroll
    for (int jt = 0; jt < 9; ++jt)
#pragma unroll
        for (int ic = 0; ic < 9; ++ic)
            at_[jt][ic] = __builtin_bit_cast(half4, Ah[(jt * 9 + ic) * 64 + l]);

    const unsigned short* ob = obs + (size_t)(blk * 16 + (l & 15)) * TLEN;
    uint4 pk = *(const uint4*)ob;           // obs t=0..7 for this lane's column
    __syncthreads();                        // sEm staged

    const h2 ones = {(half_t)1.f, (half_t)1.f};
    const f32x4 Z4 = {0.f, 0.f, 0.f, 0.f};
    half4 y_[9];
    uint2 emc[9], emn[9];
    float zp, lp, ll = 0.f;

    // ---- t = 0: Y0[i][b] = 128 * I0[i] * em[i][o0(b)] ----
    {
        int o0 = pk.x & 127;
#pragma unroll
        for (int ic = 0; ic < 9; ++ic)
            emc[ic] = *(const uint2*)&sEm[o0 * EMS + ic * 16 + g4];
        float zs = 0.f;
#pragma unroll
        for (int ic = 0; ic < 9; ++ic) {
            float4 iv = *(const float4*)&I0p[ic * 16 + g4];
            h2 e01 = bch2(emc[ic].x), e23 = bch2(emc[ic].y);
            h2 p01 = pkrtz(iv.x * (float)e01.x * 128.f, iv.y * (float)e01.y * 128.f);
            h2 p23 = pkrtz(iv.z * (float)e23.x * 128.f, iv.w * (float)e23.y * 128.f);
            y_[ic] = mk4(p01, p23);
            zs = FDOT2(p01, ones, FDOT2(p23, ones, zs));
        }
        zs = xadd16(zs);
        zs = xadd32(zs);
        zp = zs;
        lp = zs;                            // accumulates z_0
        // load em for step t=1
        int o1 = (pk.x >> 16) & 127;
#pragma unroll
        for (int ic = 0; ic < 9; ++ic)
            emc[ic] = *(const uint2*)&sEm[o1 * EMS + ic * 16 + g4];
    }

// obs element k (0..7) from a uint4 of packed u16
#define GETO(P, K) ((int)(((&(P).x)[(K) >> 1] >> (((K) & 1) * 16)) & 127))

// one HMM step. On entry: emc = em[., o_t], y_ = Y_{t-1} frags, zp = z_{t-1}.
#define STEP(O_NEXT, FOLD) do {                                               \
    const int _on = (O_NEXT);                                                 \
    _Pragma("unroll")                                                         \
    for (int ic = 0; ic < 9; ++ic)                                            \
        emn[ic] = *(const uint2*)&sEm[_on * EMS + ic * 16 + g4];              \
    const float gsc = 128.f * __builtin_amdgcn_rcpf(zp);                      \
    const half_t gh = (half_t)gsc;                                            \
    const h2 g2 = {gh, gh};                                                   \
    f32x4 d[9];                                                               \
    _Pragma("unroll")                                                         \
    for (int jt = 0; jt < 9; ++jt)                                            \
        d[jt] = __builtin_amdgcn_mfma_f32_16x16x16f16(                        \
                    at_[jt][0], y_[0], Z4, 0, 0, 0);                          \
    _Pragma("unroll")                                                         \
    for (int ic = 1; ic < 9; ++ic) {                                          \
        _Pragma("unroll")                                                     \
        for (int jt = 0; jt < 9; ++jt)                                        \
            d[jt] = __builtin_amdgcn_mfma_f32_16x16x16f16(                    \
                        at_[jt][ic], y_[ic], d[jt], 0, 0, 0);                 \
    }                                                                         \
    float za = 0.f, zb = 0.f, zc = 0.f, zd = 0.f;                             \
    _Pragma("unroll")                                                         \
    for (int jt = 0; jt < 9; ++jt) {                                          \
        h2 p01 = pkrtz(d[jt][0], d[jt][1]) * bch2(emc[jt].x) * g2;            \
        h2 p23 = pkrtz(d[jt][2], d[jt][3]) * bch2(emc[jt].y) * g2;            \
        y_[jt] = mk4(p01, p23);                                               \
        if (jt & 1) { zc = FDOT2(p01, ones, zc); zd = FDOT2(p23, ones, zd); } \
        else        { za = FDOT2(p01, ones, za); zb = FDOT2(p23, ones, zb); } \
    }                                                                         \
    float zs = (za + zb) + (zc + zd);                                         \
    zs = xadd16(zs);                                                          \
    zs = xadd32(zs);                                                          \
    zp = zs;                                                                  \
    lp *= zs;                                                                 \
    if (FOLD) { ll += __logf(lp); lp = 1.f; }                                 \
    _Pragma("unroll")                                                         \
    for (int ic = 0; ic < 9; ++ic) emc[ic] = emn[ic];                         \
} while (0)

    // ---- peeled chunk 0: steps t = 1..7 ----
    {
        uint4 pn = *(const uint4*)(ob + 8);
#pragma unroll
        for (int k = 1; k < 8; ++k) {
            int on = (k < 7) ? GETO(pk, k + 1) : (int)(pn.x & 127);
            STEP(on, (k & 3) == 3);
        }
        pk = pn;
    }

    // ---- main chunks: c = 1..1249, steps t = 8c..8c+7 ----
    for (int c = 1; c < 1250; ++c) {
        // prefetch next obs pack (c=1249 reads past row end into ws -- valid
        // memory; value masked to <=127, loaded row never used in math)
        uint4 pn = *(const uint4*)(ob + 8 * (c + 1));
#pragma unroll
        for (int k = 0; k < 8; ++k) {
            int on = (k < 7) ? GETO(pk, k + 1) : (int)(pn.x & 127);
            STEP(on, (k & 3) == 3);
        }
        pk = pn;
    }
    // folds at t=3,7,11,...,9999 -> every z_t folded exactly once

    if (l < 16) out[blk * 16 + l] = ll - 48520.302639196f;  // 10000*ln(128)
}

// ---------------------------------------------------------------------------
extern "C" void kernel_launch(void* const* d_in, const int* in_sizes, int n_in,
                              void* d_out, int out_size, void* d_ws, size_t ws_size,
                              hipStream_t stream) {
    const float* x  = (const float*)d_in[0];  // [32,10000,126] one-hot fp32
    const float* A  = (const float*)d_in[1];  // [132,132]
    const float* Bm = (const float*)d_in[2];  // [132,126]
    const float* I0 = (const float*)d_in[3];  // [132]
    float* out = (float*)d_out;               // [32] fp32

    char* ws = (char*)d_ws;
    unsigned short* obs = (unsigned short*)(ws + OBS_OFF);
    uint2*  Ah  = (uint2*)(ws + AT_OFF);
    half_t* emt = (half_t*)(ws + EM_OFF);
    float*  I0p = (float*)(ws + I0_OFF);

    const int total = NBATCH * TLEN;
    onehot_to_idx_kernel<<<(total + 3) / 4, 256, 0, stream>>>(x, obs, total);
    pack_At_kernel<<<(81 * 64 + 255) / 256, 256, 0, stream>>>(A, Ah);
    pack_em_kernel<<<(NA * EMS + 255) / 256, 256, 0, stream>>>(Bm, emt);
    pack_I0_kernel<<<1, NSP, 0, stream>>>(I0, I0p);
    hmm_mfma_kernel<<<2, 64, 0, stream>>>(Ah, emt, I0p, obs, out);
}